// Round 4
// baseline (2241.442 us; speedup 1.0000x reference)
//
#include <hip/hip_runtime.h>
#include <hip/hip_bf16.h>
#include <math.h>

// Problem constants
#define Bv 4
#define Sv 512
#define Dv 768
#define FFv 3072
#define Vv 30000
#define Vpad 30080
#define Hv 12
#define Mv 64
#define DHv 64
#define NLAYERS 12
#define QKVN 2304

typedef __attribute__((ext_vector_type(8))) short short8;   // 8 bf16 (4 VGPRs)
typedef __attribute__((ext_vector_type(4))) short short4v;  // 4 bf16 (8B store)
typedef __attribute__((ext_vector_type(4))) float floatx4;  // MFMA accumulator

// fp32 -> bf16 (round to nearest even), returned as raw short bits
static __device__ __forceinline__ short f2b(float f) {
  union { float f; unsigned u; } v; v.f = f;
  unsigned r = v.u + 0x7fffu + ((v.u >> 16) & 1u);
  return (short)(r >> 16);
}

// async 16B global -> LDS (lds dest = wave-uniform base + lane*16)
#define GLD16(gp, lp) __builtin_amdgcn_global_load_lds( \
    (__attribute__((address_space(1))) void*)(gp), \
    (__attribute__((address_space(3))) void*)(lp), 16, 0, 0)

#define VMCNT0_BARRIER() do { \
    asm volatile("s_waitcnt vmcnt(0)" ::: "memory"); \
    __builtin_amdgcn_s_barrier(); \
  } while (0)

// ---------------- weight transpose+convert: W[K][N] f32 -> Wt[Nout][K] bf16 ----------------
__global__ __launch_bounds__(256) void transpose_w(
    const float* __restrict__ W, short* __restrict__ Wt,
    int K, int N, int Nout)
{
  __shared__ float t[32][33];
  int n0 = blockIdx.x * 32, k0 = blockIdx.y * 32;
  int tx = threadIdx.x & 31, ty = threadIdx.x >> 5;   // ty 0..7
  #pragma unroll
  for (int i = 0; i < 4; i++) {
    int k = k0 + ty + i * 8, n = n0 + tx;
    t[ty + i * 8][tx] = (n < N) ? W[(size_t)k * N + n] : 0.f;
  }
  __syncthreads();
  #pragma unroll
  for (int i = 0; i < 4; i++) {
    int n = n0 + ty + i * 8, k = k0 + tx;
    if (n < Nout) Wt[(size_t)n * K + k] = f2b(t[tx][ty + i * 8]);
  }
}

__global__ __launch_bounds__(256) void pack_bias(
    const float* __restrict__ bq, const float* __restrict__ bk,
    const float* __restrict__ bv, float* __restrict__ bqkv)
{
  int i = blockIdx.x * 256 + threadIdx.x;
  if (i < Dv) { bqkv[i] = bq[i]; bqkv[Dv + i] = bk[i]; bqkv[2 * Dv + i] = bv[i]; }
}

// ---------------- embedding: x = gather(se_w, tok) + se_b + pe ----------------
__global__ __launch_bounds__(256) void embed_kernel(
    const float* __restrict__ oh, const float* __restrict__ sew,
    const float* __restrict__ seb, float* __restrict__ xf,
    short* __restrict__ xb)
{
  int bs = blockIdx.x;            // b*S + s
  int s = bs & (Sv - 1);
  __shared__ int tokS;
  const float* row = oh + (size_t)bs * Vv;
  for (int j = threadIdx.x * 4; j < Vv; j += 256 * 4) {
    float4 f = *(const float4*)(row + j);
    if (f.x != 0.f) tokS = j;
    if (f.y != 0.f) tokS = j + 1;
    if (f.z != 0.f) tokS = j + 2;
    if (f.w != 0.f) tokS = j + 3;
  }
  __syncthreads();
  int tok = tokS;
  for (int d = threadIdx.x; d < Dv; d += 256) {
    float pe = 0.f;
    if (s > 0) {
      float denom = expf(9.210340371976184f * (2.f * (float)d / 768.f));
      float raw = (float)s / denom;
      pe = (d & 1) ? cosf(raw) : sinf(raw);
    }
    float val = sew[(size_t)tok * Dv + d] + seb[d] + pe;
    xf[(size_t)bs * Dv + d] = val;
    xb[(size_t)bs * Dv + d] = f2b(val);
  }
}

// ---------------- GEMM: C[M,N] = A[M,K]bf16 @ Bt[N,K]bf16^T + bias ----------------
// BMxBNxBK tiles, 4 waves in 2x2 (WM x WN each). Grids sized <=256 blocks
// (balanced, 1 block/CU) -- the GEMMs are LDS-pipe-bound, so the 2-pass tail
// of an unbalanced grid is the dominant cost. Double-buffered GLD16 staging,
// XOR-swizzled; XCD-contiguous remap (T1) when nwg % 8 == 0.
template <int BM, int BN, int WM, int WN, int BK>
__global__ __launch_bounds__(256) void gemm_bt(
    const short* __restrict__ A, const short* __restrict__ Bt,
    const float* __restrict__ bias, float* __restrict__ Cf,
    short* __restrict__ Cb, int M, int N, int K, int relu)
{
  constexpr int CPR = BK / 8;             // 16B chunks per LDS row
  constexpr int ITA = BM * BK / 2048;     // GLD16 iters per thread (A)
  constexpr int ITB = BN * BK / 2048;
  constexpr int ITMAX = ITA > ITB ? ITA : ITB;
  __shared__ __align__(16) short As[2][BM * BK];
  __shared__ __align__(16) short Bs[2][BN * BK];

  int nwgx = gridDim.x;
  int nwg = nwgx * gridDim.y;
  int fid = blockIdx.y * nwgx + blockIdx.x;
  if ((nwg & 7) == 0) fid = (fid & 7) * (nwg >> 3) + (fid >> 3);  // XCD-contiguous
  int n0 = (fid % nwgx) * BN, m0 = (fid / nwgx) * BM;

  int tid = threadIdx.x;
  int wave = tid >> 6, lane = tid & 63, quad = lane >> 4, l16 = lane & 15;
  int wm = (wave >> 1) * WM, wn = (wave & 1) * WN;

  floatx4 acc[WM / 16][WN / 16];
  #pragma unroll
  for (int i = 0; i < WM / 16; i++)
    #pragma unroll
    for (int j = 0; j < WN / 16; j++) acc[i][j] = (floatx4){0.f, 0.f, 0.f, 0.f};

  // staging decode (chunk linear index = it*256 + tid)
  int srow[ITMAX], skc[ITMAX];
  #pragma unroll
  for (int it = 0; it < ITMAX; it++) {
    int c = it * 256 + tid;
    srow[it] = c / CPR;
    skc[it] = (c & (CPR - 1)) ^ (srow[it] & 7);
  }

  auto stage = [&](int buf, int k0) {
    #pragma unroll
    for (int it = 0; it < ITA; it++)
      GLD16(A + (size_t)(m0 + srow[it]) * K + k0 + skc[it] * 8,
            &As[buf][it * 2048 + wave * 512]);
    #pragma unroll
    for (int it = 0; it < ITB; it++)
      GLD16(Bt + (size_t)(n0 + srow[it]) * K + k0 + skc[it] * 8,
            &Bs[buf][it * 2048 + wave * 512]);
  };

  int nt = K / BK;
  stage(0, 0);
  VMCNT0_BARRIER();
  int cur = 0;
  for (int t = 0; t < nt; t++) {
    if (t + 1 < nt) stage(cur ^ 1, (t + 1) * BK);   // prefetch under compute
    #pragma unroll
    for (int kh = 0; kh < BK / 32; kh++) {
      short8 af[WM / 16], bfr[WN / 16];
      int kc = kh * 4 + quad;
      #pragma unroll
      for (int i = 0; i < WM / 16; i++) {
        int ra = wm + i * 16 + l16;
        af[i] = *(const short8*)(&As[cur][(ra * CPR + (kc ^ (ra & 7))) * 8]);
      }
      #pragma unroll
      for (int j = 0; j < WN / 16; j++) {
        int rb = wn + j * 16 + l16;
        bfr[j] = *(const short8*)(&Bs[cur][(rb * CPR + (kc ^ (rb & 7))) * 8]);
      }
      #pragma unroll
      for (int i = 0; i < WM / 16; i++)
        #pragma unroll
        for (int j = 0; j < WN / 16; j++)
          acc[i][j] = __builtin_amdgcn_mfma_f32_16x16x32_bf16(af[i], bfr[j], acc[i][j], 0, 0, 0);
    }
    VMCNT0_BARRIER();
    cur ^= 1;
  }

  // C/D: col = l16, row = quad*4 + reg
  #pragma unroll
  for (int i = 0; i < WM / 16; i++) {
    int row = m0 + wm + i * 16 + quad * 4;
    #pragma unroll
    for (int j = 0; j < WN / 16; j++) {
      int col = n0 + wn + j * 16 + l16;
      if (col < N) {
        float bb = bias ? bias[col] : 0.f;
        #pragma unroll
        for (int r = 0; r < 4; r++) {
          float val = acc[i][j][r] + bb;
          if (relu) val = fmaxf(val, 0.f);
          size_t off = (size_t)(row + r) * N + col;
          if (Cf) Cf[off] = val;
          if (Cb) Cb[off] = f2b(val);
        }
      }
    }
  }
}

// ---------------- vocab GEMM: C[M,N] = A[M,K]bf16 @ B[K,N]f32 + bias ----------------
// Reads we f32 directly (no pre-transpose kernel): B-tile staged through regs,
// converted to bf16, written transposed+swizzled into LDS. BM=BN=128, BK=64.
__global__ __launch_bounds__(256) void gemm_bf32(
    const short* __restrict__ A, const float* __restrict__ B,
    const float* __restrict__ bias, float* __restrict__ Cf,
    int M, int N, int K)
{
  __shared__ __align__(16) short As[128 * 64];
  __shared__ __align__(16) short Bs[128 * 64];
  int n0 = blockIdx.x * 128, m0 = blockIdx.y * 128;
  int tid = threadIdx.x;
  int wave = tid >> 6, lane = tid & 63, quad = lane >> 4, l16 = lane & 15;
  int wm = (wave >> 1) * 64, wn = (wave & 1) * 64;

  floatx4 acc[4][4];
  #pragma unroll
  for (int i = 0; i < 4; i++)
    #pragma unroll
    for (int j = 0; j < 4; j++) acc[i][j] = (floatx4){0.f, 0.f, 0.f, 0.f};

  int srow[4], skc[4];
  #pragma unroll
  for (int it = 0; it < 4; it++) {
    int c = it * 256 + tid;
    srow[it] = c >> 3;
    skc[it] = (c & 7) ^ (srow[it] & 7);
  }
  int bk0 = tid >> 5;          // 0..7: base k-row
  int bn  = (tid & 31) * 4;    // n within tile

  for (int k0 = 0; k0 < K; k0 += 64) {
    __syncthreads();
    #pragma unroll
    for (int it = 0; it < 4; it++)
      GLD16(A + (size_t)(m0 + srow[it]) * K + k0 + skc[it] * 8,
            As + (it * 2048 + wave * 512));
    // B: 8 rows x float4, transpose+convert into Bs[n][k] (swizzled)
    #pragma unroll
    for (int i = 0; i < 8; i++) {
      int kk = k0 + bk0 + i * 8;
      int ng = n0 + bn;
      float4 bv;
      if (ng + 3 < N) bv = *(const float4*)(B + (size_t)kk * N + ng);
      else {
        bv.x = (ng     < N) ? B[(size_t)kk * N + ng]     : 0.f;
        bv.y = (ng + 1 < N) ? B[(size_t)kk * N + ng + 1] : 0.f;
        bv.z = (ng + 2 < N) ? B[(size_t)kk * N + ng + 2] : 0.f;
        bv.w = (ng + 3 < N) ? B[(size_t)kk * N + ng + 3] : 0.f;
      }
      // element (n, k): Bs[n*64 + ((i ^ (n&7))<<3) + bk0]  (k>>3 == i, k&7 == bk0)
      int nA = bn,     nB = bn + 1, nC = bn + 2, nD = bn + 3;
      Bs[nA * 64 + ((i ^ (nA & 7)) << 3) + bk0] = f2b(bv.x);
      Bs[nB * 64 + ((i ^ (nB & 7)) << 3) + bk0] = f2b(bv.y);
      Bs[nC * 64 + ((i ^ (nC & 7)) << 3) + bk0] = f2b(bv.z);
      Bs[nD * 64 + ((i ^ (nD & 7)) << 3) + bk0] = f2b(bv.w);
    }
    __syncthreads();
    #pragma unroll
    for (int kh = 0; kh < 2; kh++) {
      short8 af[4], bfr[4];
      int kc = kh * 4 + quad;
      #pragma unroll
      for (int i = 0; i < 4; i++) {
        int ra = wm + i * 16 + l16;
        af[i] = *(const short8*)(As + (ra * 8 + (kc ^ (ra & 7))) * 8);
      }
      #pragma unroll
      for (int j = 0; j < 4; j++) {
        int rb = wn + j * 16 + l16;
        bfr[j] = *(const short8*)(Bs + (rb * 8 + (kc ^ (rb & 7))) * 8);
      }
      #pragma unroll
      for (int i = 0; i < 4; i++)
        #pragma unroll
        for (int j = 0; j < 4; j++)
          acc[i][j] = __builtin_amdgcn_mfma_f32_16x16x32_bf16(af[i], bfr[j], acc[i][j], 0, 0, 0);
    }
  }

  #pragma unroll
  for (int i = 0; i < 4; i++) {
    int row = m0 + wm + i * 16 + quad * 4;
    #pragma unroll
    for (int j = 0; j < 4; j++) {
      int col = n0 + wn + j * 16 + l16;
      if (col < N) {
        float bb = bias[col];
        #pragma unroll
        for (int r = 0; r < 4; r++)
          Cf[(size_t)(row + r) * N + col] = acc[i][j][r] + bb;
      }
    }
  }
}

// ---------------- fused attention: O = softmax(scale*Q K^T) V, one (b,h,q-tile) per block --------
__global__ __launch_bounds__(256) void attn_fused(
    const short* __restrict__ qkv, short* __restrict__ O)
{
  __shared__ __align__(16) short lv[64 * 512];     // swizzled V^T: element (n,k)
  __shared__ __align__(16) short pbuf[4][16][40];  // per-wave P chunk, A-layout

  // XCD-contiguous remap: 8 q-tiles sharing one (b,h)'s K/V land on one XCD
  int fid = blockIdx.y * gridDim.x + blockIdx.x;            // grid (8, 48)
  fid = (fid & 7) * 48 + (fid >> 3);
  int q0 = (fid & 7) * 64;
  int bh = fid >> 3;
  int b = bh / Hv, h = bh - b * Hv;
  int tid = threadIdx.x;
  int wave = tid >> 6, lane = tid & 63, quad = lane >> 4, l16 = lane & 15;

  floatx4 acc[32];
  #pragma unroll
  for (int c = 0; c < 32; c++) acc[c] = (floatx4){0.f, 0.f, 0.f, 0.f};

  const short* Qrow = qkv + (size_t)(b * Sv + q0 + wave * 16 + l16) * QKVN + h * DHv;
  short8 a0 = *(const short8*)(Qrow + quad * 8);
  short8 a1 = *(const short8*)(Qrow + 32 + quad * 8);
  const short* Kbase = qkv + Dv + (size_t)(b * Sv + l16) * QKVN + h * DHv + quad * 8;
  const short* Vbase = qkv + 2 * Dv + h * DHv + (size_t)(b * Sv) * QKVN;

  // V staging decode: thread covers rows kb_t + 8i of each 128-row quarter, cols n2_t..n2_t+1
  int kb_t = tid >> 5;            // 0..7
  int n2_t = (tid & 31) * 2;      // even 0..62
  short2 vreg[16];

  // swizzle: element (n,k) at lv[n*512 + sch*8 + (k&7)], sch = (ch&~7)|((ch^n)&7), ch=k>>3
#define LOADQ(qi) do { \
    _Pragma("unroll") \
    for (int i = 0; i < 16; i++) { \
      int kk = (qi) * 128 + i * 8 + kb_t; \
      vreg[i] = *(const short2*)(Vbase + (size_t)kk * QKVN + n2_t); \
    } } while (0)
#define WRITEQ(qi) do { \
    _Pragma("unroll") \
    for (int i = 0; i < 16; i++) { \
      int ch = (qi) * 16 + i; \
      int sw0 = (ch & ~7) | ((ch ^ n2_t) & 7); \
      lv[n2_t * 512 + sw0 * 8 + kb_t] = vreg[i].x; \
      lv[(n2_t + 1) * 512 + (sw0 ^ 1) * 8 + kb_t] = vreg[i].y; \
    } } while (0)

  // Phase 1: QK^T in 4 groups of 8 chunks; V-quarter loads issued under each group
  #pragma unroll
  for (int g = 0; g < 4; g++) {
    if (g > 0) WRITEQ(g - 1);
    LOADQ(g);
    #pragma unroll
    for (int cc = 0; cc < 8; cc++) {
      int c = g * 8 + cc;
      const short* Kp = Kbase + (size_t)c * 16 * QKVN;
      short8 b0 = *(const short8*)(Kp);
      short8 b1 = *(const short8*)(Kp + 32);
      acc[c] = __builtin_amdgcn_mfma_f32_16x16x32_bf16(a0, b0, acc[c], 0, 0, 0);
      acc[c] = __builtin_amdgcn_mfma_f32_16x16x32_bf16(a1, b1, acc[c], 0, 0, 0);
    }
  }

  float inv[4];
  #pragma unroll
  for (int r = 0; r < 4; r++) {
    float m = -1e30f;
    #pragma unroll
    for (int c = 0; c < 32; c++) m = fmaxf(m, acc[c][r]);
    m = fmaxf(m, __shfl_xor(m, 1));
    m = fmaxf(m, __shfl_xor(m, 2));
    m = fmaxf(m, __shfl_xor(m, 4));
    m = fmaxf(m, __shfl_xor(m, 8));
    float s = 0.f;
    #pragma unroll
    for (int c = 0; c < 32; c++) {
      float e = __expf((acc[c][r] - m) * 0.125f);
      acc[c][r] = e; s += e;
    }
    s += __shfl_xor(s, 1);
    s += __shfl_xor(s, 2);
    s += __shfl_xor(s, 4);
    s += __shfl_xor(s, 8);
    inv[r] = 1.f / s;
  }

  WRITEQ(3);
  __syncthreads();               // the ONLY barrier: all lv writes done

  // Phase 2: O[16x64 per wave] = P @ V, no barriers
  floatx4 acc_o[4];
  #pragma unroll
  for (int j = 0; j < 4; j++) acc_o[j] = (floatx4){0.f, 0.f, 0.f, 0.f};

  #pragma unroll
  for (int kc = 0; kc < 16; kc++) {      // k0 = kc*32
    #pragma unroll
    for (int half = 0; half < 2; half++) {
      int c = 2 * kc + half;
      #pragma unroll
      for (int r = 0; r < 4; r++)
        pbuf[wave][quad * 4 + r][half * 16 + l16] = f2b(acc[c][r] * inv[r]);
    }
    short8 af = *(const short8*)(&pbuf[wave][l16][quad * 8]);
    #pragma unroll
    for (int j = 0; j < 4; j++) {
      int n = j * 16 + l16;
      int ch = kc * 4 + quad;
      int sw = (ch & ~7) | ((ch ^ n) & 7);
      short8 bf = *(const short8*)(lv + n * 512 + sw * 8);
      acc_o[j] = __builtin_amdgcn_mfma_f32_16x16x32_bf16(af, bf, acc_o[j], 0, 0, 0);
    }
  }
#undef LOADQ
#undef WRITEQ

  int row = q0 + wave * 16 + quad * 4;
  #pragma unroll
  for (int j = 0; j < 4; j++) {
    int col = h * DHv + j * 16 + l16;
    #pragma unroll
    for (int r = 0; r < 4; r++)
      O[(size_t)(b * Sv + row + r) * Dv + col] = f2b(acc_o[j][r]);
  }
}

// ---------------- residual add + layernorm: wave-per-row, shfl-only, float4 ----------------
__global__ __launch_bounds__(256) void addln_kernel(
    float* __restrict__ xf, const float* __restrict__ mh,
    short* __restrict__ xb)
{
  int wave = threadIdx.x >> 6, lane = threadIdx.x & 63;
  int r = blockIdx.x * 4 + wave;
  size_t base = (size_t)r * Dv;
  float4 v[3];
  float s = 0.f;
  #pragma unroll
  for (int i = 0; i < 3; i++) {
    int j = (lane + i * 64) * 4;
    float4 a = *(const float4*)(xf + base + j);
    float4 b = *(const float4*)(mh + base + j);
    v[i].x = a.x + b.x; v[i].y = a.y + b.y;
    v[i].z = a.z + b.z; v[i].w = a.w + b.w;
    s += v[i].x + v[i].y + v[i].z + v[i].w;
  }
  #pragma unroll
  for (int o = 32; o > 0; o >>= 1) s += __shfl_xor(s, o);
  float mean = s * (1.f / 768.f);
  float q = 0.f;
  #pragma unroll
  for (int i = 0; i < 3; i++) {
    float dx = v[i].x - mean, dy = v[i].y - mean;
    float dz = v[i].z - mean, dw = v[i].w - mean;
    q += dx * dx + dy * dy + dz * dz + dw * dw;
  }
  #pragma unroll
  for (int o = 32; o > 0; o >>= 1) q += __shfl_xor(q, o);
  float inv = rsqrtf(q * (1.f / 768.f) + 1e-5f);
  #pragma unroll
  for (int i = 0; i < 3; i++) {
    int j = (lane + i * 64) * 4;
    float4 o4;
    o4.x = (v[i].x - mean) * inv; o4.y = (v[i].y - mean) * inv;
    o4.z = (v[i].z - mean) * inv; o4.w = (v[i].w - mean) * inv;
    *(float4*)(xf + base + j) = o4;
    short4v b4 = { f2b(o4.x), f2b(o4.y), f2b(o4.z), f2b(o4.w) };
    *(short4v*)(xb + base + j) = b4;
  }
}

// ---------------- gather masked rows ----------------
__global__ __launch_bounds__(256) void gather_kernel(
    const short* __restrict__ xb, const int* __restrict__ idx,
    short* __restrict__ g)
{
  int bm = blockIdx.x;            // b*M + m
  int b = bm >> 6;
  int s = idx[bm];
  for (int d = threadIdx.x; d < Dv; d += 256)
    g[(size_t)bm * Dv + d] = xb[(size_t)(b * Sv + s) * Dv + d];
}

// ---------------- log_softmax over V=30000 (float4 passes) ----------------
__global__ __launch_bounds__(256) void lsm_kernel(
    const float* __restrict__ L, float* __restrict__ out)
{
  int r = blockIdx.x, t = threadIdx.x;
  const float4* p4 = (const float4*)(L + (size_t)r * Vv);   // Vv % 4 == 0
  float m = -1e30f;
  for (int j = t; j < Vv / 4; j += 256) {
    float4 f = p4[j];
    m = fmaxf(m, fmaxf(fmaxf(f.x, f.y), fmaxf(f.z, f.w)));
  }
  __shared__ float red[256];
  red[t] = m;
  __syncthreads();
  for (int s2 = 128; s2 > 0; s2 >>= 1) { if (t < s2) red[t] = fmaxf(red[t], red[t + s2]); __syncthreads(); }
  m = red[0];
  __syncthreads();
  float s = 0.f;
  for (int j = t; j < Vv / 4; j += 256) {
    float4 f = p4[j];
    s += expf(f.x - m) + expf(f.y - m) + expf(f.z - m) + expf(f.w - m);
  }
  red[t] = s;
  __syncthreads();
  for (int s2 = 128; s2 > 0; s2 >>= 1) { if (t < s2) red[t] += red[t + s2]; __syncthreads(); }
  float lse = m + logf(red[0]);
  float4* o4 = (float4*)(out + (size_t)r * Vv);
  for (int j = t; j < Vv / 4; j += 256) {
    float4 f = p4[j];
    f.x -= lse; f.y -= lse; f.z -= lse; f.w -= lse;
    o4[j] = f;
  }
}

extern "C" void kernel_launch(void* const* d_in, const int* in_sizes, int n_in,
                              void* d_out, int out_size, void* d_ws, size_t ws_size,
                              hipStream_t stream) {
  const float* oh  = (const float*)d_in[0];
  const float* sew = (const float*)d_in[1];
  const float* seb = (const float*)d_in[2];
  const float* wq  = (const float*)d_in[3];  const float* bq = (const float*)d_in[4];
  const float* wk  = (const float*)d_in[5];  const float* bk = (const float*)d_in[6];
  const float* wv  = (const float*)d_in[7];  const float* bv = (const float*)d_in[8];
  const float* wo  = (const float*)d_in[9];  const float* bo = (const float*)d_in[10];
  const float* w1  = (const float*)d_in[11]; const float* b1 = (const float*)d_in[12];
  const float* w2  = (const float*)d_in[13]; const float* b2 = (const float*)d_in[14];
  const float* we  = (const float*)d_in[15]; const float* be = (const float*)d_in[16];
  const int*   idx = (const int*)d_in[17];
  float* out = (float*)d_out;

  // workspace carve (256B aligned)
  char* p = (char*)d_ws;
  auto alloc = [&](size_t bytes) -> char* {
    char* r = p; p += (bytes + 255) & ~(size_t)255; return r;
  };
  const size_t BS = (size_t)Bv * Sv;                       // 2048
  short* wqkv_t = (short*)alloc((size_t)QKVN * Dv * 2);    // [2304][768] bf16
  short* wo_t   = (short*)alloc((size_t)Dv * Dv * 2);      // [768][768]
  short* w1_t   = (short*)alloc((size_t)FFv * Dv * 2);     // [3072][768]
  short* w2_t   = (short*)alloc((size_t)Dv * FFv * 2);     // [768][3072]
  float* bqkv   = (float*)alloc(QKVN * 4);
  short* xb     = (short*)alloc(BS * Dv * 2);              // bf16 trunk mirror
  float* xf     = (float*)alloc(BS * Dv * 4);              // fp32 trunk
  short* g      = (short*)alloc((size_t)Bv * Mv * Dv * 2);
  char*  TR     = p;                                        // transient union
  // layer-phase views
  short* qkv   = (short*)TR;                                          // [2048][2304] bf16
  short* o     = (short*)(TR + ((BS * QKVN * 2 + 255) & ~(size_t)255));
  float* mh    = (float*)((char*)o + ((BS * Dv * 2 + 255) & ~(size_t)255));
  short* t1    = (short*)((char*)mh + ((BS * Dv * 4 + 255) & ~(size_t)255));
  // final-phase view (aliases the dead layer buffers)
  float* lg    = (float*)TR;                                          // [256][30000] f32

  // ---- one-time weight preprocessing (bf16, transposed) ----
  transpose_w<<<dim3(24, 24), 256, 0, stream>>>(wq, wqkv_t,            Dv, Dv, Dv);
  transpose_w<<<dim3(24, 24), 256, 0, stream>>>(wk, wqkv_t + Dv * Dv,  Dv, Dv, Dv);
  transpose_w<<<dim3(24, 24), 256, 0, stream>>>(wv, wqkv_t + 2*Dv*Dv,  Dv, Dv, Dv);
  transpose_w<<<dim3(24, 24), 256, 0, stream>>>(wo, wo_t,              Dv, Dv, Dv);
  transpose_w<<<dim3(96, 24), 256, 0, stream>>>(w1, w1_t,              Dv, FFv, FFv);
  transpose_w<<<dim3(24, 96), 256, 0, stream>>>(w2, w2_t,              FFv, Dv, Dv);
  pack_bias<<<3, 256, 0, stream>>>(bq, bk, bv, bqkv);

  embed_kernel<<<(int)BS, 256, 0, stream>>>(oh, sew, seb, xf, xb);

  // Balanced grids (<=256 blocks, 1 block/CU; all %8==0 for the XCD remap)
  dim3 gQKV(QKVN / 192, (int)BS / 128);   // (12, 16) = 192 blocks, BN=192
  dim3 gD64(Dv / 64, (int)BS / 128);      // (12, 16) = 192 blocks (N=768 GEMMs, BM=128)
  dim3 gFF(FFv / 192, (int)BS / 128);     // (16, 16) = 256 blocks, BN=192
  for (int l = 0; l < NLAYERS; l++) {
    gemm_bt<128,192,64,96,64><<<gQKV, 256, 0, stream>>>(xb, wqkv_t, bqkv, nullptr, qkv, (int)BS, QKVN, Dv, 0);
    attn_fused<<<dim3(Sv / 64, Bv * Hv), 256, 0, stream>>>(qkv, o);
    gemm_bt<128,64,64,32,128><<<gD64, 256, 0, stream>>>(o, wo_t, bo, mh, nullptr, (int)BS, Dv, Dv, 0);
    addln_kernel<<<(int)BS / 4, 256, 0, stream>>>(xf, mh, xb);
    gemm_bt<128,192,64,96,64><<<gFF, 256, 0, stream>>>(xb, w1_t, b1, nullptr, t1, (int)BS, FFv, Dv, 1);
    gemm_bt<128,64,64,32,128><<<gD64, 256, 0, stream>>>(t1, w2_t, b2, xf, xb, (int)BS, Dv, FFv, 0);
  }

  // vocab projection straight from f32 we (no pre-transpose)
  gather_kernel<<<Bv * Mv, 256, 0, stream>>>(xb, idx, g);
  gemm_bf32<<<dim3(Vpad / 128, (Bv * Mv) / 128), 256, 0, stream>>>(
      g, we, be, lg, Bv * Mv, Vv, Dv);
  lsm_kernel<<<Bv * Mv, 256, 0, stream>>>(lg, out);
}

// Round 5
// 1948.918 us; speedup vs baseline: 1.1501x; 1.1501x over previous
//
#include <hip/hip_runtime.h>
#include <hip/hip_bf16.h>
#include <math.h>

// Problem constants
#define Bv 4
#define Sv 512
#define Dv 768
#define FFv 3072
#define Vv 30000
#define Vpad 30080
#define Hv 12
#define Mv 64
#define DHv 64
#define NLAYERS 12
#define QKVN 2304

typedef __attribute__((ext_vector_type(8))) short short8;   // 8 bf16 (4 VGPRs)
typedef __attribute__((ext_vector_type(4))) short short4v;  // 4 bf16 (8B store)
typedef __attribute__((ext_vector_type(4))) float floatx4;  // MFMA accumulator

// fp32 -> bf16 (round to nearest even), returned as raw short bits
static __device__ __forceinline__ short f2b(float f) {
  union { float f; unsigned u; } v; v.f = f;
  unsigned r = v.u + 0x7fffu + ((v.u >> 16) & 1u);
  return (short)(r >> 16);
}

// async 16B global -> LDS (lds dest = wave-uniform base + lane*16)
#define GLD16(gp, lp) __builtin_amdgcn_global_load_lds( \
    (__attribute__((address_space(1))) void*)(gp), \
    (__attribute__((address_space(3))) void*)(lp), 16, 0, 0)

#define VMCNT0_BARRIER() do { \
    asm volatile("s_waitcnt vmcnt(0)" ::: "memory"); \
    __builtin_amdgcn_s_barrier(); \
  } while (0)

// ---------------- merged one-time prep: 6 weight transposes + bias pack + embed --------------
// All pieces are mutually independent; dispatched by blockIdx range in ONE launch
// so the embed's 245 MB one-hot scan overlaps the transpose work.
static __device__ __forceinline__ void transpose_piece(
    const float* __restrict__ W, short* __restrict__ Wt,
    int K, int N, int Nout, int bx, int by)
{
  __shared__ float t[32][33];
  int n0 = bx * 32, k0 = by * 32;
  int tx = threadIdx.x & 31, ty = threadIdx.x >> 5;   // ty 0..7
  #pragma unroll
  for (int i = 0; i < 4; i++) {
    int k = k0 + ty + i * 8, n = n0 + tx;
    t[ty + i * 8][tx] = (n < N) ? W[(size_t)k * N + n] : 0.f;
  }
  __syncthreads();
  #pragma unroll
  for (int i = 0; i < 4; i++) {
    int n = n0 + ty + i * 8, k = k0 + tx;
    if (n < Nout) Wt[(size_t)n * K + k] = f2b(t[tx][ty + i * 8]);
  }
}

__global__ __launch_bounds__(256) void prep_kernel(
    const float* __restrict__ wq, const float* __restrict__ wk,
    const float* __restrict__ wv, const float* __restrict__ wo,
    const float* __restrict__ w1, const float* __restrict__ w2,
    const float* __restrict__ bq, const float* __restrict__ bk,
    const float* __restrict__ bv,
    const float* __restrict__ oh, const float* __restrict__ sew,
    const float* __restrict__ seb,
    short* __restrict__ wqkv_t, short* __restrict__ wo_t,
    short* __restrict__ w1_t, short* __restrict__ w2_t,
    float* __restrict__ bqkv,
    float* __restrict__ xf, short* __restrict__ xb)
{
  int bid = blockIdx.x;
  if (bid < 2304) {                 // q/k/v/wo transposes: 4 x 576 (grid 24x24)
    int which = bid / 576, r = bid - which * 576;
    int bx = r % 24, by = r / 24;
    const float* W = (which == 0) ? wq : (which == 1) ? wk : (which == 2) ? wv : wo;
    short* Wt = (which < 3) ? (wqkv_t + which * Dv * Dv) : wo_t;
    transpose_piece(W, Wt, Dv, Dv, Dv, bx, by);
  } else if (bid < 4608) {          // w1: grid (96, 24)
    int r = bid - 2304;
    transpose_piece(w1, w1_t, Dv, FFv, FFv, r % 96, r / 96);
  } else if (bid < 6912) {          // w2: grid (24, 96)
    int r = bid - 4608;
    transpose_piece(w2, w2_t, FFv, Dv, Dv, r % 24, r / 24);
  } else if (bid < 6915) {          // pack_bias: 3 blocks
    int i = (bid - 6912) * 256 + threadIdx.x;
    if (i < Dv) { bqkv[i] = bq[i]; bqkv[Dv + i] = bk[i]; bqkv[2 * Dv + i] = bv[i]; }
  } else {                          // embed: 2048 blocks
    int bs = bid - 6915;            // b*S + s
    int s = bs & (Sv - 1);
    __shared__ int tokS;
    const float* row = oh + (size_t)bs * Vv;
    for (int j = threadIdx.x * 4; j < Vv; j += 256 * 4) {
      float4 f = *(const float4*)(row + j);
      if (f.x != 0.f) tokS = j;
      if (f.y != 0.f) tokS = j + 1;
      if (f.z != 0.f) tokS = j + 2;
      if (f.w != 0.f) tokS = j + 3;
    }
    __syncthreads();
    int tok = tokS;
    for (int d = threadIdx.x; d < Dv; d += 256) {
      float pe = 0.f;
      if (s > 0) {
        float denom = expf(9.210340371976184f * (2.f * (float)d / 768.f));
        float raw = (float)s / denom;
        pe = (d & 1) ? cosf(raw) : sinf(raw);
      }
      float val = sew[(size_t)tok * Dv + d] + seb[d] + pe;
      xf[(size_t)bs * Dv + d] = val;
      xb[(size_t)bs * Dv + d] = f2b(val);
    }
  }
}

// ---------------- GEMM: C[M,N] = A[M,K]bf16 @ Bt[N,K]bf16^T + bias ----------------
// R3 config (proven): 128x128 BK64 / 64x64 BK128, dbuf GLD16 staging, 64 KB LDS
// -> 2 blocks/CU co-residency. XOR-swizzled; XCD-contiguous remap when nwg%8==0.
template <int BM, int BN, int WM, int WN, int BK>
__global__ __launch_bounds__(256) void gemm_bt(
    const short* __restrict__ A, const short* __restrict__ Bt,
    const float* __restrict__ bias, float* __restrict__ Cf,
    short* __restrict__ Cb, int M, int N, int K, int relu)
{
  constexpr int CPR = BK / 8;             // 16B chunks per LDS row
  constexpr int ITA = BM * BK / 2048;     // GLD16 iters per thread (A)
  constexpr int ITB = BN * BK / 2048;
  constexpr int ITMAX = ITA > ITB ? ITA : ITB;
  __shared__ __align__(16) short As[2][BM * BK];
  __shared__ __align__(16) short Bs[2][BN * BK];

  int nwgx = gridDim.x;
  int nwg = nwgx * gridDim.y;
  int fid = blockIdx.y * nwgx + blockIdx.x;
  if ((nwg & 7) == 0) fid = (fid & 7) * (nwg >> 3) + (fid >> 3);  // XCD-contiguous
  int n0 = (fid % nwgx) * BN, m0 = (fid / nwgx) * BM;

  int tid = threadIdx.x;
  int wave = tid >> 6, lane = tid & 63, quad = lane >> 4, l16 = lane & 15;
  int wm = (wave >> 1) * WM, wn = (wave & 1) * WN;

  floatx4 acc[WM / 16][WN / 16];
  #pragma unroll
  for (int i = 0; i < WM / 16; i++)
    #pragma unroll
    for (int j = 0; j < WN / 16; j++) acc[i][j] = (floatx4){0.f, 0.f, 0.f, 0.f};

  // staging decode (chunk linear index = it*256 + tid)
  int srow[ITMAX], skc[ITMAX];
  #pragma unroll
  for (int it = 0; it < ITMAX; it++) {
    int c = it * 256 + tid;
    srow[it] = c / CPR;
    skc[it] = (c & (CPR - 1)) ^ (srow[it] & 7);
  }

  auto stage = [&](int buf, int k0) {
    #pragma unroll
    for (int it = 0; it < ITA; it++)
      GLD16(A + (size_t)(m0 + srow[it]) * K + k0 + skc[it] * 8,
            &As[buf][it * 2048 + wave * 512]);
    #pragma unroll
    for (int it = 0; it < ITB; it++)
      GLD16(Bt + (size_t)(n0 + srow[it]) * K + k0 + skc[it] * 8,
            &Bs[buf][it * 2048 + wave * 512]);
  };

  int nt = K / BK;
  stage(0, 0);
  VMCNT0_BARRIER();
  int cur = 0;
  for (int t = 0; t < nt; t++) {
    if (t + 1 < nt) stage(cur ^ 1, (t + 1) * BK);   // prefetch under compute
    #pragma unroll
    for (int kh = 0; kh < BK / 32; kh++) {
      short8 af[WM / 16], bfr[WN / 16];
      int kc = kh * 4 + quad;
      #pragma unroll
      for (int i = 0; i < WM / 16; i++) {
        int ra = wm + i * 16 + l16;
        af[i] = *(const short8*)(&As[cur][(ra * CPR + (kc ^ (ra & 7))) * 8]);
      }
      #pragma unroll
      for (int j = 0; j < WN / 16; j++) {
        int rb = wn + j * 16 + l16;
        bfr[j] = *(const short8*)(&Bs[cur][(rb * CPR + (kc ^ (rb & 7))) * 8]);
      }
      #pragma unroll
      for (int i = 0; i < WM / 16; i++)
        #pragma unroll
        for (int j = 0; j < WN / 16; j++)
          acc[i][j] = __builtin_amdgcn_mfma_f32_16x16x32_bf16(af[i], bfr[j], acc[i][j], 0, 0, 0);
    }
    VMCNT0_BARRIER();
    cur ^= 1;
  }

  // C/D: col = l16, row = quad*4 + reg
  #pragma unroll
  for (int i = 0; i < WM / 16; i++) {
    int row = m0 + wm + i * 16 + quad * 4;
    #pragma unroll
    for (int j = 0; j < WN / 16; j++) {
      int col = n0 + wn + j * 16 + l16;
      if (col < N) {
        float bb = bias ? bias[col] : 0.f;
        #pragma unroll
        for (int r = 0; r < 4; r++) {
          float val = acc[i][j][r] + bb;
          if (relu) val = fmaxf(val, 0.f);
          size_t off = (size_t)(row + r) * N + col;
          if (Cf) Cf[off] = val;
          if (Cb) Cb[off] = f2b(val);
        }
      }
    }
  }
}

// ---------------- vocab GEMM (gather fused): C[M,N] = xb[idx][K]bf16 @ B[K,N]f32 + bias ----
// A-rows indirect through idx (gather folded in). B staged through regs -> bf16
// transposed+swizzled LDS. BM=BN=128, BK=64.
__global__ __launch_bounds__(256) void gemm_bf32(
    const short* __restrict__ xb, const int* __restrict__ idx,
    const float* __restrict__ B, const float* __restrict__ bias,
    float* __restrict__ Cf, int M, int N, int K)
{
  __shared__ __align__(16) short As[128 * 64];
  __shared__ __align__(16) short Bs[128 * 64];
  int n0 = blockIdx.x * 128, m0 = blockIdx.y * 128;
  int tid = threadIdx.x;
  int wave = tid >> 6, lane = tid & 63, quad = lane >> 4, l16 = lane & 15;
  int wm = (wave >> 1) * 64, wn = (wave & 1) * 64;

  floatx4 acc[4][4];
  #pragma unroll
  for (int i = 0; i < 4; i++)
    #pragma unroll
    for (int j = 0; j < 4; j++) acc[i][j] = (floatx4){0.f, 0.f, 0.f, 0.f};

  size_t abase[4]; int skc[4];
  #pragma unroll
  for (int it = 0; it < 4; it++) {
    int c = it * 256 + tid;
    int srow = c >> 3;
    skc[it] = (c & 7) ^ (srow & 7);
    int arow = m0 + srow;                  // 0..255 = b*M + m
    int b = arow >> 6;
    abase[it] = (size_t)(b * Sv + idx[arow]) * Dv;
  }
  int bk0 = tid >> 5;          // 0..7: base k-row
  int bn  = (tid & 31) * 4;    // n within tile

  for (int k0 = 0; k0 < K; k0 += 64) {
    __syncthreads();
    #pragma unroll
    for (int it = 0; it < 4; it++)
      GLD16(xb + abase[it] + k0 + skc[it] * 8,
            As + (it * 2048 + wave * 512));
    // B: 8 rows x float4, transpose+convert into Bs[n][k] (swizzled)
    #pragma unroll
    for (int i = 0; i < 8; i++) {
      int kk = k0 + bk0 + i * 8;
      int ng = n0 + bn;
      float4 bv;
      if (ng + 3 < N) bv = *(const float4*)(B + (size_t)kk * N + ng);
      else {
        bv.x = (ng     < N) ? B[(size_t)kk * N + ng]     : 0.f;
        bv.y = (ng + 1 < N) ? B[(size_t)kk * N + ng + 1] : 0.f;
        bv.z = (ng + 2 < N) ? B[(size_t)kk * N + ng + 2] : 0.f;
        bv.w = (ng + 3 < N) ? B[(size_t)kk * N + ng + 3] : 0.f;
      }
      // element (n, k): Bs[n*64 + ((i ^ (n&7))<<3) + bk0]  (k>>3 == i, k&7 == bk0)
      int nA = bn,     nB = bn + 1, nC = bn + 2, nD = bn + 3;
      Bs[nA * 64 + ((i ^ (nA & 7)) << 3) + bk0] = f2b(bv.x);
      Bs[nB * 64 + ((i ^ (nB & 7)) << 3) + bk0] = f2b(bv.y);
      Bs[nC * 64 + ((i ^ (nC & 7)) << 3) + bk0] = f2b(bv.z);
      Bs[nD * 64 + ((i ^ (nD & 7)) << 3) + bk0] = f2b(bv.w);
    }
    __syncthreads();
    #pragma unroll
    for (int kh = 0; kh < 2; kh++) {
      short8 af[4], bfr[4];
      int kc = kh * 4 + quad;
      #pragma unroll
      for (int i = 0; i < 4; i++) {
        int ra = wm + i * 16 + l16;
        af[i] = *(const short8*)(As + (ra * 8 + (kc ^ (ra & 7))) * 8);
      }
      #pragma unroll
      for (int j = 0; j < 4; j++) {
        int rb = wn + j * 16 + l16;
        bfr[j] = *(const short8*)(Bs + (rb * 8 + (kc ^ (rb & 7))) * 8);
      }
      #pragma unroll
      for (int i = 0; i < 4; i++)
        #pragma unroll
        for (int j = 0; j < 4; j++)
          acc[i][j] = __builtin_amdgcn_mfma_f32_16x16x32_bf16(af[i], bfr[j], acc[i][j], 0, 0, 0);
    }
  }

  #pragma unroll
  for (int i = 0; i < 4; i++) {
    int row = m0 + wm + i * 16 + quad * 4;
    #pragma unroll
    for (int j = 0; j < 4; j++) {
      int col = n0 + wn + j * 16 + l16;
      if (col < N) {
        float bb = bias[col];
        #pragma unroll
        for (int r = 0; r < 4; r++)
          Cf[(size_t)(row + r) * N + col] = acc[i][j][r] + bb;
      }
    }
  }
}

// ---------------- fused attention: O = softmax(scale*Q K^T) V, one (b,h,q-tile) per block --------
__global__ __launch_bounds__(256) void attn_fused(
    const short* __restrict__ qkv, short* __restrict__ O)
{
  __shared__ __align__(16) short lv[64 * 512];     // swizzled V^T: element (n,k)
  __shared__ __align__(16) short pbuf[4][16][40];  // per-wave P chunk, A-layout

  // XCD-contiguous remap: 8 q-tiles sharing one (b,h)'s K/V land on one XCD
  int fid = blockIdx.y * gridDim.x + blockIdx.x;            // grid (8, 48)
  fid = (fid & 7) * 48 + (fid >> 3);
  int q0 = (fid & 7) * 64;
  int bh = fid >> 3;
  int b = bh / Hv, h = bh - b * Hv;
  int tid = threadIdx.x;
  int wave = tid >> 6, lane = tid & 63, quad = lane >> 4, l16 = lane & 15;

  floatx4 acc[32];
  #pragma unroll
  for (int c = 0; c < 32; c++) acc[c] = (floatx4){0.f, 0.f, 0.f, 0.f};

  const short* Qrow = qkv + (size_t)(b * Sv + q0 + wave * 16 + l16) * QKVN + h * DHv;
  short8 a0 = *(const short8*)(Qrow + quad * 8);
  short8 a1 = *(const short8*)(Qrow + 32 + quad * 8);
  const short* Kbase = qkv + Dv + (size_t)(b * Sv + l16) * QKVN + h * DHv + quad * 8;
  const short* Vbase = qkv + 2 * Dv + h * DHv + (size_t)(b * Sv) * QKVN;

  // V staging decode: thread covers rows kb_t + 8i of each 128-row quarter, cols n2_t..n2_t+1
  int kb_t = tid >> 5;            // 0..7
  int n2_t = (tid & 31) * 2;      // even 0..62
  short2 vreg[16];

  // swizzle: element (n,k) at lv[n*512 + sch*8 + (k&7)], sch = (ch&~7)|((ch^n)&7), ch=k>>3
#define LOADQ(qi) do { \
    _Pragma("unroll") \
    for (int i = 0; i < 16; i++) { \
      int kk = (qi) * 128 + i * 8 + kb_t; \
      vreg[i] = *(const short2*)(Vbase + (size_t)kk * QKVN + n2_t); \
    } } while (0)
#define WRITEQ(qi) do { \
    _Pragma("unroll") \
    for (int i = 0; i < 16; i++) { \
      int ch = (qi) * 16 + i; \
      int sw0 = (ch & ~7) | ((ch ^ n2_t) & 7); \
      lv[n2_t * 512 + sw0 * 8 + kb_t] = vreg[i].x; \
      lv[(n2_t + 1) * 512 + (sw0 ^ 1) * 8 + kb_t] = vreg[i].y; \
    } } while (0)

  // Phase 1: QK^T in 4 groups of 8 chunks; V-quarter loads issued under each group
  #pragma unroll
  for (int g = 0; g < 4; g++) {
    if (g > 0) WRITEQ(g - 1);
    LOADQ(g);
    #pragma unroll
    for (int cc = 0; cc < 8; cc++) {
      int c = g * 8 + cc;
      const short* Kp = Kbase + (size_t)c * 16 * QKVN;
      short8 b0 = *(const short8*)(Kp);
      short8 b1 = *(const short8*)(Kp + 32);
      acc[c] = __builtin_amdgcn_mfma_f32_16x16x32_bf16(a0, b0, acc[c], 0, 0, 0);
      acc[c] = __builtin_amdgcn_mfma_f32_16x16x32_bf16(a1, b1, acc[c], 0, 0, 0);
    }
  }

  float inv[4];
  #pragma unroll
  for (int r = 0; r < 4; r++) {
    float m = -1e30f;
    #pragma unroll
    for (int c = 0; c < 32; c++) m = fmaxf(m, acc[c][r]);
    m = fmaxf(m, __shfl_xor(m, 1));
    m = fmaxf(m, __shfl_xor(m, 2));
    m = fmaxf(m, __shfl_xor(m, 4));
    m = fmaxf(m, __shfl_xor(m, 8));
    float s = 0.f;
    #pragma unroll
    for (int c = 0; c < 32; c++) {
      float e = __expf((acc[c][r] - m) * 0.125f);
      acc[c][r] = e; s += e;
    }
    s += __shfl_xor(s, 1);
    s += __shfl_xor(s, 2);
    s += __shfl_xor(s, 4);
    s += __shfl_xor(s, 8);
    inv[r] = 1.f / s;
  }

  WRITEQ(3);
  __syncthreads();               // the ONLY barrier: all lv writes done

  // Phase 2: O[16x64 per wave] = P @ V, no barriers
  floatx4 acc_o[4];
  #pragma unroll
  for (int j = 0; j < 4; j++) acc_o[j] = (floatx4){0.f, 0.f, 0.f, 0.f};

  #pragma unroll
  for (int kc = 0; kc < 16; kc++) {      // k0 = kc*32
    #pragma unroll
    for (int half = 0; half < 2; half++) {
      int c = 2 * kc + half;
      #pragma unroll
      for (int r = 0; r < 4; r++)
        pbuf[wave][quad * 4 + r][half * 16 + l16] = f2b(acc[c][r] * inv[r]);
    }
    short8 af = *(const short8*)(&pbuf[wave][l16][quad * 8]);
    #pragma unroll
    for (int j = 0; j < 4; j++) {
      int n = j * 16 + l16;
      int ch = kc * 4 + quad;
      int sw = (ch & ~7) | ((ch ^ n) & 7);
      short8 bf = *(const short8*)(lv + n * 512 + sw * 8);
      acc_o[j] = __builtin_amdgcn_mfma_f32_16x16x32_bf16(af, bf, acc_o[j], 0, 0, 0);
    }
  }
#undef LOADQ
#undef WRITEQ

  int row = q0 + wave * 16 + quad * 4;
  #pragma unroll
  for (int j = 0; j < 4; j++) {
    int col = h * DHv + j * 16 + l16;
    #pragma unroll
    for (int r = 0; r < 4; r++)
      O[(size_t)(b * Sv + row + r) * Dv + col] = f2b(acc_o[j][r]);
  }
}

// ---------------- residual add + layernorm: wave-per-row, shfl-only, float4 ----------------
__global__ __launch_bounds__(256) void addln_kernel(
    float* __restrict__ xf, const float* __restrict__ mh,
    short* __restrict__ xb)
{
  int wave = threadIdx.x >> 6, lane = threadIdx.x & 63;
  int r = blockIdx.x * 4 + wave;
  size_t base = (size_t)r * Dv;
  float4 v[3];
  float s = 0.f;
  #pragma unroll
  for (int i = 0; i < 3; i++) {
    int j = (lane + i * 64) * 4;
    float4 a = *(const float4*)(xf + base + j);
    float4 b = *(const float4*)(mh + base + j);
    v[i].x = a.x + b.x; v[i].y = a.y + b.y;
    v[i].z = a.z + b.z; v[i].w = a.w + b.w;
    s += v[i].x + v[i].y + v[i].z + v[i].w;
  }
  #pragma unroll
  for (int o = 32; o > 0; o >>= 1) s += __shfl_xor(s, o);
  float mean = s * (1.f / 768.f);
  float q = 0.f;
  #pragma unroll
  for (int i = 0; i < 3; i++) {
    float dx = v[i].x - mean, dy = v[i].y - mean;
    float dz = v[i].z - mean, dw = v[i].w - mean;
    q += dx * dx + dy * dy + dz * dz + dw * dw;
  }
  #pragma unroll
  for (int o = 32; o > 0; o >>= 1) q += __shfl_xor(q, o);
  float inv = rsqrtf(q * (1.f / 768.f) + 1e-5f);
  #pragma unroll
  for (int i = 0; i < 3; i++) {
    int j = (lane + i * 64) * 4;
    float4 o4;
    o4.x = (v[i].x - mean) * inv; o4.y = (v[i].y - mean) * inv;
    o4.z = (v[i].z - mean) * inv; o4.w = (v[i].w - mean) * inv;
    *(float4*)(xf + base + j) = o4;
    short4v b4 = { f2b(o4.x), f2b(o4.y), f2b(o4.z), f2b(o4.w) };
    *(short4v*)(xb + base + j) = b4;
  }
}

// ---------------- log_softmax over V=30000 (float4 passes) ----------------
__global__ __launch_bounds__(256) void lsm_kernel(
    const float* __restrict__ L, float* __restrict__ out)
{
  int r = blockIdx.x, t = threadIdx.x;
  const float4* p4 = (const float4*)(L + (size_t)r * Vv);   // Vv % 4 == 0
  float m = -1e30f;
  for (int j = t; j < Vv / 4; j += 256) {
    float4 f = p4[j];
    m = fmaxf(m, fmaxf(fmaxf(f.x, f.y), fmaxf(f.z, f.w)));
  }
  __shared__ float red[256];
  red[t] = m;
  __syncthreads();
  for (int s2 = 128; s2 > 0; s2 >>= 1) { if (t < s2) red[t] = fmaxf(red[t], red[t + s2]); __syncthreads(); }
  m = red[0];
  __syncthreads();
  float s = 0.f;
  for (int j = t; j < Vv / 4; j += 256) {
    float4 f = p4[j];
    s += expf(f.x - m) + expf(f.y - m) + expf(f.z - m) + expf(f.w - m);
  }
  red[t] = s;
  __syncthreads();
  for (int s2 = 128; s2 > 0; s2 >>= 1) { if (t < s2) red[t] += red[t + s2]; __syncthreads(); }
  float lse = m + logf(red[0]);
  float4* o4 = (float4*)(out + (size_t)r * Vv);
  for (int j = t; j < Vv / 4; j += 256) {
    float4 f = p4[j];
    f.x -= lse; f.y -= lse; f.z -= lse; f.w -= lse;
    o4[j] = f;
  }
}

extern "C" void kernel_launch(void* const* d_in, const int* in_sizes, int n_in,
                              void* d_out, int out_size, void* d_ws, size_t ws_size,
                              hipStream_t stream) {
  const float* oh  = (const float*)d_in[0];
  const float* sew = (const float*)d_in[1];
  const float* seb = (const float*)d_in[2];
  const float* wq  = (const float*)d_in[3];  const float* bq = (const float*)d_in[4];
  const float* wk  = (const float*)d_in[5];  const float* bk = (const float*)d_in[6];
  const float* wv  = (const float*)d_in[7];  const float* bv = (const float*)d_in[8];
  const float* wo  = (const float*)d_in[9];  const float* bo = (const float*)d_in[10];
  const float* w1  = (const float*)d_in[11]; const float* b1 = (const float*)d_in[12];
  const float* w2  = (const float*)d_in[13]; const float* b2 = (const float*)d_in[14];
  const float* we  = (const float*)d_in[15]; const float* be = (const float*)d_in[16];
  const int*   idx = (const int*)d_in[17];
  float* out = (float*)d_out;

  // workspace carve (256B aligned)
  char* p = (char*)d_ws;
  auto alloc = [&](size_t bytes) -> char* {
    char* r = p; p += (bytes + 255) & ~(size_t)255; return r;
  };
  const size_t BS = (size_t)Bv * Sv;                       // 2048
  short* wqkv_t = (short*)alloc((size_t)QKVN * Dv * 2);    // [2304][768] bf16
  short* wo_t   = (short*)alloc((size_t)Dv * Dv * 2);      // [768][768]
  short* w1_t   = (short*)alloc((size_t)FFv * Dv * 2);     // [3072][768]
  short* w2_t   = (short*)alloc((size_t)Dv * FFv * 2);     // [768][3072]
  float* bqkv   = (float*)alloc(QKVN * 4);
  short* xb     = (short*)alloc(BS * Dv * 2);              // bf16 trunk mirror
  float* xf     = (float*)alloc(BS * Dv * 4);              // fp32 trunk
  char*  TR     = p;                                        // transient union
  // layer-phase views
  short* qkv   = (short*)TR;                                          // [2048][2304] bf16
  short* o     = (short*)(TR + ((BS * QKVN * 2 + 255) & ~(size_t)255));
  float* mh    = (float*)((char*)o + ((BS * Dv * 2 + 255) & ~(size_t)255));
  short* t1    = (short*)((char*)mh + ((BS * Dv * 4 + 255) & ~(size_t)255));
  // final-phase view (aliases the dead layer buffers)
  float* lg    = (float*)TR;                                          // [256][30000] f32

  // ---- one merged prep launch: 6 transposes + bias pack + embed ----
  prep_kernel<<<8963, 256, 0, stream>>>(
      wq, wk, wv, wo, w1, w2, bq, bk, bv, oh, sew, seb,
      wqkv_t, wo_t, w1_t, w2_t, bqkv, xf, xb);

  dim3 gQKV(QKVN / 128, (int)BS / 128);   // (18, 16) = 288 blocks
  dim3 gD64(Dv / 64, (int)BS / 64);       // (12, 32) = 384 blocks (N=768 GEMMs)
  dim3 gFF(FFv / 128, (int)BS / 128);     // (24, 16) = 384 blocks
  for (int l = 0; l < NLAYERS; l++) {
    gemm_bt<128,128,64,64,64><<<gQKV, 256, 0, stream>>>(xb, wqkv_t, bqkv, nullptr, qkv, (int)BS, QKVN, Dv, 0);
    attn_fused<<<dim3(Sv / 64, Bv * Hv), 256, 0, stream>>>(qkv, o);
    gemm_bt<64,64,32,32,128><<<gD64, 256, 0, stream>>>(o, wo_t, bo, mh, nullptr, (int)BS, Dv, Dv, 0);
    addln_kernel<<<(int)BS / 4, 256, 0, stream>>>(xf, mh, xb);
    gemm_bt<128,128,64,64,64><<<gFF, 256, 0, stream>>>(xb, w1_t, b1, nullptr, t1, (int)BS, FFv, Dv, 1);
    gemm_bt<64,64,32,32,128><<<gD64, 256, 0, stream>>>(t1, w2_t, b2, xf, xb, (int)BS, Dv, FFv, 0);
  }

  // vocab projection straight from f32 we (gather fused into A-staging)
  gemm_bf32<<<dim3(Vpad / 128, (Bv * Mv) / 128), 256, 0, stream>>>(
      xb, idx, we, be, lg, Bv * Mv, Vv, Dv);
  lsm_kernel<<<Bv * Mv, 256, 0, stream>>>(lg, out);
}